// Round 10
// baseline (320.555 us; speedup 1.0000x reference)
//
#include <hip/hip_runtime.h>

// DeepseekV3MoEToA2AAdapter: T=2048 tokens, H=1024, E=8, I=1408, top-2.
// fp32 I/O. Block-range fusion (R6): prep = router || wtrans(g/u);
// gateup_wd = gateup || wtrans(down). DMA staging via global_load_lds
// width=16 (R9). R10: 128x128 GEMM tiles (m97-proven shape): 4 waves,
// 64x64 per wave, 32 (gateup, fused g+u) / 16 (down) MFMA per K-step per
// wave against the same barrier count -> 2x MFMA:stage ratio.
#define T_TOK 2048
#define HDIM  1024
#define NEXP  8
#define IDIM  1408

#define BM 128
#define BK 32
#define MT_SLOTS 16
#define GU_NT 11    // IDIM / 128
#define DN_NT 8     // HDIM / 128
#define DK_HALF 704 // IDIM / 2 (split-K for down)

#define GU_BLOCKS   (8 * GU_NT * MT_SLOTS)   // 1408
#define PREP_RTR    512
#define PREP_GRID   (PREP_RTR + 16 * 176)    // 3328
#define GUWD_GRID   (GU_BLOCKS + 8 * 176)    // 2816
#define DN_GRID     (8 * 2 * DN_NT * MT_SLOTS) // 2048

// gateup_wd shared-memory layout (bytes); union with wtrans tb (16896 B)
#define SM_A    0          // 128*32*2 = 8192
#define SM_G    8192       // 8192
#define SM_U    16384      // 8192
#define SM_GR   24576      // 512
#define SM_OR   25088      // 512
#define SM_SZ   25600

typedef __attribute__((ext_vector_type(8))) short bf16x8;
typedef __attribute__((ext_vector_type(4))) float f32x4;

static __device__ __forceinline__ unsigned short f2bf(float f) {
    union { float f; unsigned u; } a; a.f = f;
    return (unsigned short)((a.u + 0x7fffu + ((a.u >> 16) & 1u)) >> 16);
}

// direct global->LDS DMA, 16 B per lane; LDS dest wave-uniform base + lane*16,
// global src per-lane (gather-capable).
#define GLOAD16(gsrc, ldst)                                                  \
    __builtin_amdgcn_global_load_lds(                                        \
        (const __attribute__((address_space(1))) unsigned int*)(gsrc),       \
        (__attribute__((address_space(3))) unsigned int*)(ldst), 16, 0, 0)

// ---------------------------------------------------------------- prep ------
// blocks [0,512): router pass 1. blocks [512,3328): gate/up cast+transpose.
__global__ __launch_bounds__(256) void prep_kernel(
    const float* __restrict__ x,        // [T, H]
    const float* __restrict__ rw,       // [H, E]
    const float* __restrict__ gw,       // [E][H][I] fp32
    const float* __restrict__ uw,       // [E][H][I] fp32
    int*   __restrict__ sel,            // [T]
    float* __restrict__ w1arr,          // [T]
    unsigned short* __restrict__ xb,    // [T, H] bf16
    unsigned short* __restrict__ gwt,   // [E][I][H] bf16
    unsigned short* __restrict__ uwt)   // [E][I][H] bf16
{
    __shared__ __align__(16) char smem[32768];
    const int tid = threadIdx.x;
    const int bx  = blockIdx.x;

    if (bx < PREP_RTR) {
        float (*rwT)[HDIM] = (float (*)[HDIM])smem;   // 32 KB
#pragma unroll
        for (int p = 0; p < 4; ++p) {
            const int h = tid + 256 * p;
            const float4 a = *(const float4*)(rw + (size_t)h * 8);
            const float4 b = *(const float4*)(rw + (size_t)h * 8 + 4);
            rwT[0][h] = a.x; rwT[1][h] = a.y; rwT[2][h] = a.z; rwT[3][h] = a.w;
            rwT[4][h] = b.x; rwT[5][h] = b.y; rwT[6][h] = b.z; rwT[7][h] = b.w;
        }
        __syncthreads();

        const int t    = bx * 4 + (tid >> 6);
        const int lane = tid & 63;
        if (t >= T_TOK) return;

        float xr[16];
        const float* xp = x + (size_t)t * HDIM;
#pragma unroll
        for (int i = 0; i < 16; ++i) xr[i] = xp[lane + 64 * i];

        unsigned short* xbp = xb + (size_t)t * HDIM;
#pragma unroll
        for (int i = 0; i < 16; ++i) xbp[lane + 64 * i] = f2bf(xr[i]);

        double logits[NEXP];
#pragma unroll
        for (int e = 0; e < NEXP; ++e) {
            double s = 0.0;
#pragma unroll
            for (int i = 0; i < 16; ++i)
                s += (double)xr[i] * (double)rwT[e][lane + 64 * i];
#pragma unroll
            for (int off = 32; off > 0; off >>= 1)
                s += __shfl_down(s, off, 64);
            logits[e] = s;
        }

        if (lane == 0) {
            int e1 = 0;
            for (int e = 1; e < NEXP; ++e) if (logits[e] > logits[e1]) e1 = e;
            int e2 = -1;
            for (int e = 0; e < NEXP; ++e) {
                if (e == e1) continue;
                if (e2 < 0 || logits[e] > logits[e2]) e2 = e;
            }
            const double w1 = 1.0 / (1.0 + exp(logits[e2] - logits[e1]));
            sel[t]   = e1 | (e2 << 8);
            w1arr[t] = (float)w1;
        }
    } else {
        const int idx = bx - PREP_RTR;
        const int z   = idx / 176;          // 0..15
        const int b   = idx - z * 176;      // 0..175
        const int e   = z & 7;
        const float* src = (z < 8 ? gw : uw) + (size_t)e * HDIM * IDIM;
        unsigned short* dst =
            (z < 8 ? gwt : uwt) + (size_t)e * (size_t)IDIM * HDIM;
        const int nb = b % 11, kb = b / 11;  // 11 n-tiles x 16 k-tiles
        const int k0 = kb * 64, n0 = nb * 128;

        unsigned short (*tb)[66] = (unsigned short (*)[66])smem; // 16.9 KB

        const int lk = tid >> 5;            // 0..7
        const int ln = (tid & 31) * 4;      // 0..124
#pragma unroll
        for (int r = 0; r < 8; ++r) {
            const int k = r * 8 + lk;
            const float4 v =
                *(const float4*)(src + (size_t)(k0 + k) * IDIM + n0 + ln);
            tb[ln + 0][k] = f2bf(v.x);
            tb[ln + 1][k] = f2bf(v.y);
            tb[ln + 2][k] = f2bf(v.z);
            tb[ln + 3][k] = f2bf(v.w);
        }
        __syncthreads();

        const int wn = tid >> 3;            // 0..31
        const int wk = (tid & 7) * 8;       // 0..56
#pragma unroll
        for (int p = 0; p < 4; ++p) {
            const int n = p * 32 + wn;
            const unsigned* rp = (const unsigned*)&tb[n][wk];
            uint4 o;
            o.x = rp[0]; o.y = rp[1]; o.z = rp[2]; o.w = rp[3];
            *(uint4*)(dst + (size_t)(n0 + n) * HDIM + k0 + wk) = o;
        }
    }
}

// ------------------------------------------- router pass 2: scatter ---------
__global__ __launch_bounds__(1024) void router_scatter_kernel(
    const int* __restrict__ sel, const float* __restrict__ w1arr,
    int* __restrict__ counts,
    int* __restrict__ tok_list, float* __restrict__ wgt_list,
    int* __restrict__ row_list)
{
    __shared__ int cnt[NEXP];
    const int tid = threadIdx.x;
    if (tid < NEXP) cnt[tid] = 0;
    __syncthreads();
    for (int t = tid; t < T_TOK; t += 1024) {
        const int s  = sel[t];
        const int e1 = s & 255, e2 = s >> 8;
        const float w1 = w1arr[t];
        const int p1 = atomicAdd(&cnt[e1], 1);
        tok_list[e1 * T_TOK + p1] = t;
        wgt_list[e1 * T_TOK + p1] = w1;
        row_list[e1 * T_TOK + p1] = 2 * t;
        const int p2 = atomicAdd(&cnt[e2], 1);
        tok_list[e2 * T_TOK + p2] = t;
        wgt_list[e2 * T_TOK + p2] = 1.0f - w1;
        row_list[e2 * T_TOK + p2] = 2 * t + 1;
    }
    __syncthreads();
    if (tid < NEXP) counts[tid] = cnt[tid];
}

// -------------------------------- fused gate+up GEMM || wtrans(down) --------
// blocks [0,1408): gateup 128x128/BK=32, 4 waves each 64x64 per matrix,
// DMA staging (6 global_load_lds per wave per K-step), acc[4][4] x {g,u}.
// blocks [1408,2816): down_proj cast+transpose.
__global__ __launch_bounds__(256) void gateup_wd_kernel(
    const unsigned short* __restrict__ xb,    // [T,H] bf16
    const unsigned short* __restrict__ gwt,   // [E][I][H] bf16
    const unsigned short* __restrict__ uwt,   // [E][I][H] bf16
    const float* __restrict__ gb, const float* __restrict__ ub,
    const int* __restrict__ counts,
    const int* __restrict__ tok_list,
    const int* __restrict__ row_list,
    unsigned short* __restrict__ act,         // [2T, IDIM] bf16
    const float* __restrict__ dw,             // [E][I][H] fp32
    unsigned short* __restrict__ dwt)         // [E][H][I] bf16
{
    __shared__ __align__(16) char smem[SM_SZ];
    const int tid  = threadIdx.x;
    const int flat = blockIdx.x;

    if (flat >= GU_BLOCKS) {
        // ------------------------------ wtrans down ---------------------
        const int idx = flat - GU_BLOCKS;
        const int e   = idx / 176;
        const int b   = idx - e * 176;
        const float* src = dw + (size_t)e * IDIM * HDIM;   // [I][H] fp32
        unsigned short* dst = dwt + (size_t)e * (size_t)HDIM * IDIM;
        const int nb = b & 7, kb = b >> 3;   // 8 n-tiles x 22 k-tiles
        const int k0 = kb * 64, n0 = nb * 128;

        unsigned short (*tb)[66] = (unsigned short (*)[66])smem;

        const int lk = tid >> 5;
        const int ln = (tid & 31) * 4;
#pragma unroll
        for (int r = 0; r < 8; ++r) {
            const int k = r * 8 + lk;
            const float4 v =
                *(const float4*)(src + (size_t)(k0 + k) * HDIM + n0 + ln);
            tb[ln + 0][k] = f2bf(v.x);
            tb[ln + 1][k] = f2bf(v.y);
            tb[ln + 2][k] = f2bf(v.z);
            tb[ln + 3][k] = f2bf(v.w);
        }
        __syncthreads();

        const int wn = tid >> 3;
        const int wk = (tid & 7) * 8;
#pragma unroll
        for (int p = 0; p < 4; ++p) {
            const int n = p * 32 + wn;
            const unsigned* rp = (const unsigned*)&tb[n][wk];
            uint4 o;
            o.x = rp[0]; o.y = rp[1]; o.z = rp[2]; o.w = rp[3];
            *(uint4*)(dst + (size_t)(n0 + n) * IDIM + k0 + wk) = o;
        }
        return;
    }

    // ---------------------------------- gateup (128x128, DMA) -----------
    unsigned short (*As)[32] = (unsigned short (*)[32])(smem + SM_A);
    unsigned short (*Bg)[32] = (unsigned short (*)[32])(smem + SM_G);
    unsigned short (*Bu)[32] = (unsigned short (*)[32])(smem + SM_U);
    int* gr_lds = (int*)(smem + SM_GR);
    int* or_lds = (int*)(smem + SM_OR);

    const int xcd  = flat & 7;
    const int q    = flat >> 3;
    const int mt   = q & 15;
    const int slot = q >> 4;           // 0..10
    const int P    = slot * 8 + xcd;   // 0..87 = (e, nt)
    const int e    = P / GU_NT;
    const int nt   = P % GU_NT;
    const int n_e  = counts[e];
    const int m0   = mt * BM;
    if (m0 >= n_e) return;
    const int n0 = nt * 128;

    const unsigned short* gwp = gwt + (size_t)e * IDIM * HDIM;
    const unsigned short* uwp = uwt + (size_t)e * IDIM * HDIM;
    const float* gbp = gb + (size_t)e * IDIM;
    const float* ubp = ub + (size_t)e * IDIM;

    const int base = e * T_TOK;
    if (tid < BM) {
        const int m = m0 + tid;
        int g = -1, o = -1;
        if (m < n_e) { g = tok_list[base + m]; o = row_list[base + m]; }
        gr_lds[tid] = g; or_lds[tid] = o;
    }
    __syncthreads();

    const int wv = tid >> 6, lane = tid & 63;
    const int lr = lane >> 2;           // 0..15 (row within 16-row segment)
    const int lc = (lane & 3) * 8;      // col element (16 B chunks)

    // A: 2 segments per wave (gathered token rows)
    const int r0 = 32 * wv + lr;
    const int r1 = r0 + 16;
    int a0 = gr_lds[r0]; if (a0 < 0) a0 = 0;
    int a1 = gr_lds[r1]; if (a1 < 0) a1 = 0;
    const unsigned short* apA0 = xb + (size_t)a0 * HDIM + lc;
    const unsigned short* apA1 = xb + (size_t)a1 * HDIM + lc;
    unsigned short* dA0 = &As[32 * wv][0];
    unsigned short* dA1 = &As[32 * wv + 16][0];
    // B: 2 segments per wave per matrix (128 weight rows)
    const unsigned short* gpB0 = gwp + (size_t)(n0 + r0) * HDIM + lc;
    const unsigned short* gpB1 = gwp + (size_t)(n0 + r1) * HDIM + lc;
    const unsigned short* upB0 = uwp + (size_t)(n0 + r0) * HDIM + lc;
    const unsigned short* upB1 = uwp + (size_t)(n0 + r1) * HDIM + lc;
    unsigned short* dBg0 = &Bg[32 * wv][0];
    unsigned short* dBg1 = &Bg[32 * wv + 16][0];
    unsigned short* dBu0 = &Bu[32 * wv][0];
    unsigned short* dBu1 = &Bu[32 * wv + 16][0];

    const int wm = (wv & 1) * 64, wn = (wv >> 1) * 64;
    const int l16 = lane & 15, quad = lane >> 4;

    f32x4 accg[4][4], accu[4][4];
    const f32x4 zero = {0.0f, 0.0f, 0.0f, 0.0f};
#pragma unroll
    for (int i = 0; i < 4; ++i)
#pragma unroll
        for (int j = 0; j < 4; ++j) { accg[i][j] = zero; accu[i][j] = zero; }

    for (int k0 = 0; k0 < HDIM; k0 += BK) {
        __syncthreads();                 // previous tile fully consumed
        GLOAD16(apA0 + k0, dA0);
        GLOAD16(apA1 + k0, dA1);
        GLOAD16(gpB0 + k0, dBg0);
        GLOAD16(gpB1 + k0, dBg1);
        GLOAD16(upB0 + k0, dBu0);
        GLOAD16(upB1 + k0, dBu1);
        __syncthreads();                 // vmcnt(0) drain -> LDS valid

        bf16x8 af[4], bgf[4], buf_[4];
#pragma unroll
        for (int i = 0; i < 4; ++i)
            af[i] = *(const bf16x8*)&As[wm + i * 16 + l16][quad * 8];
#pragma unroll
        for (int j = 0; j < 4; ++j) {
            bgf[j]  = *(const bf16x8*)&Bg[wn + j * 16 + l16][quad * 8];
            buf_[j] = *(const bf16x8*)&Bu[wn + j * 16 + l16][quad * 8];
        }
#pragma unroll
        for (int i = 0; i < 4; ++i)
#pragma unroll
            for (int j = 0; j < 4; ++j) {
                accg[i][j] = __builtin_amdgcn_mfma_f32_16x16x32_bf16(
                    af[i], bgf[j], accg[i][j], 0, 0, 0);
                accu[i][j] = __builtin_amdgcn_mfma_f32_16x16x32_bf16(
                    af[i], buf_[j], accu[i][j], 0, 0, 0);
            }
    }

    // epilogue: silu(g)*u -> bf16 act
#pragma unroll
    for (int j = 0; j < 4; ++j) {
        const int nl = n0 + wn + j * 16 + l16;
        const float gbv = gbp[nl];
        const float ubv = ubp[nl];
#pragma unroll
        for (int i = 0; i < 4; ++i) {
#pragma unroll
            for (int ii = 0; ii < 4; ++ii) {
                const int ml = wm + i * 16 + quad * 4 + ii;
                const int orow = or_lds[ml];
                if (orow >= 0) {
                    const float g = accg[i][j][ii] + gbv;
                    const float uu = accu[i][j][ii] + ubv;
                    act[(size_t)orow * IDIM + nl] =
                        f2bf(g * uu / (1.0f + __expf(-g)));
                }
            }
        }
    }
}

// ------------------------------------------------------- down-proj GEMM ----
// Split-K=2, NON-ATOMIC; 128x128 tile, DMA staging, acc[4][4] (m97 shape).
__global__ __launch_bounds__(256) void down_kernel(
    const unsigned short* __restrict__ act,   // [2T, IDIM] bf16
    const unsigned short* __restrict__ dwt,   // [E][H][I] bf16
    const float* __restrict__ db,
    const int* __restrict__ counts,
    const float* __restrict__ wgt_list,
    const int* __restrict__ row_list,
    float* __restrict__ y2)                   // [2][2T, HDIM] fp32
{
    const int flat = blockIdx.x;
    const int xcd  = flat & 7;
    const int q    = flat >> 3;
    const int mt   = q & 15;
    const int slot = q >> 4;           // 0..15
    const int P    = slot * 8 + xcd;   // 0..127 = (sk, e, nt)
    const int sk   = P & 1;
    const int en   = P >> 1;           // 0..63
    const int e    = en >> 3;
    const int nt   = en & 7;
    const int n_e  = counts[e];
    const int m0   = mt * BM;
    if (m0 >= n_e) return;
    const int n0 = nt * 128;
    const int ks = sk * DK_HALF;
    float* y2s = y2 + (size_t)sk * 2 * T_TOK * HDIM;

    const unsigned short* dwp = dwt + (size_t)e * HDIM * IDIM;
    const float* dbp = db + (size_t)e * HDIM;

    __shared__ unsigned short As[BM][32];    // 8 KB
    __shared__ unsigned short Bs[128][32];   // 8 KB
    __shared__ int   r_lds[BM];
    __shared__ float w_lds[BM];

    const int tid = threadIdx.x;
    const int base = e * T_TOK;
    if (tid < BM) {
        const int m = m0 + tid;
        int r = -1; float w = 0.0f;
        if (m < n_e) { r = row_list[base + m]; w = wgt_list[base + m]; }
        r_lds[tid] = r; w_lds[tid] = w;
    }
    __syncthreads();

    const int wv = tid >> 6, lane = tid & 63;
    const int lr = lane >> 2;
    const int lc = (lane & 3) * 8;

    const int r0 = 32 * wv + lr;
    const int r1 = r0 + 16;
    int a0 = r_lds[r0]; if (a0 < 0) a0 = 0;
    int a1 = r_lds[r1]; if (a1 < 0) a1 = 0;
    const unsigned short* apA0 = act + (size_t)a0 * IDIM + ks + lc;
    const unsigned short* apA1 = act + (size_t)a1 * IDIM + ks + lc;
    unsigned short* dA0 = &As[32 * wv][0];
    unsigned short* dA1 = &As[32 * wv + 16][0];
    const unsigned short* bpB0 = dwp + (size_t)(n0 + r0) * IDIM + ks + lc;
    const unsigned short* bpB1 = dwp + (size_t)(n0 + r1) * IDIM + ks + lc;
    unsigned short* dB0 = &Bs[32 * wv][0];
    unsigned short* dB1 = &Bs[32 * wv + 16][0];

    const int wm = (wv & 1) * 64, wn = (wv >> 1) * 64;
    const int l16 = lane & 15, quad = lane >> 4;

    f32x4 acc[4][4];
    const f32x4 zero = {0.0f, 0.0f, 0.0f, 0.0f};
#pragma unroll
    for (int i = 0; i < 4; ++i)
#pragma unroll
        for (int j = 0; j < 4; ++j) acc[i][j] = zero;

    for (int k0 = 0; k0 < DK_HALF; k0 += BK) {
        __syncthreads();
        GLOAD16(apA0 + k0, dA0);
        GLOAD16(apA1 + k0, dA1);
        GLOAD16(bpB0 + k0, dB0);
        GLOAD16(bpB1 + k0, dB1);
        __syncthreads();

        bf16x8 af[4], bfr[4];
#pragma unroll
        for (int i = 0; i < 4; ++i)
            af[i] = *(const bf16x8*)&As[wm + i * 16 + l16][quad * 8];
#pragma unroll
        for (int j = 0; j < 4; ++j)
            bfr[j] = *(const bf16x8*)&Bs[wn + j * 16 + l16][quad * 8];
#pragma unroll
        for (int i = 0; i < 4; ++i)
#pragma unroll
            for (int j = 0; j < 4; ++j)
                acc[i][j] = __builtin_amdgcn_mfma_f32_16x16x32_bf16(
                    af[i], bfr[j], acc[i][j], 0, 0, 0);
    }

#pragma unroll
    for (int j = 0; j < 4; ++j) {
        const int nl = n0 + wn + j * 16 + l16;
        const float bv = (sk == 0) ? dbp[nl] : 0.0f;
#pragma unroll
        for (int i = 0; i < 4; ++i) {
#pragma unroll
            for (int ii = 0; ii < 4; ++ii) {
                const int ml = wm + i * 16 + quad * 4 + ii;
                const int rr = r_lds[ml];
                if (rr >= 0)
                    y2s[(size_t)rr * HDIM + nl] = w_lds[ml] * (acc[i][j][ii] + bv);
            }
        }
    }
}

// --------------------------------------------------------------- combine ----
__global__ __launch_bounds__(256) void combine_kernel(
    const float* __restrict__ y2, float* __restrict__ out)
{
    const int idx = (blockIdx.x * 256 + threadIdx.x) * 4;   // < T*H
    const int t = idx >> 10;           // HDIM == 1024
    const int h = idx & 1023;
    const float* y2b = y2 + (size_t)2 * T_TOK * HDIM;
    const float4 a0 = *(const float4*)(y2  + ((size_t)2 * t) * HDIM + h);
    const float4 a1 = *(const float4*)(y2  + ((size_t)2 * t + 1) * HDIM + h);
    const float4 b0 = *(const float4*)(y2b + ((size_t)2 * t) * HDIM + h);
    const float4 b1 = *(const float4*)(y2b + ((size_t)2 * t + 1) * HDIM + h);
    float4 o;
    o.x = a0.x + a1.x + b0.x + b1.x;
    o.y = a0.y + a1.y + b0.y + b1.y;
    o.z = a0.z + a1.z + b0.z + b1.z;
    o.w = a0.w + a1.w + b0.w + b1.w;
    *(float4*)(out + idx) = o;
}

// ---------------------------------------------------------------- launch ----
extern "C" void kernel_launch(void* const* d_in, const int* in_sizes, int n_in,
                              void* d_out, int out_size, void* d_ws, size_t ws_size,
                              hipStream_t stream)
{
    const float* x      = (const float*)d_in[0];
    const float* rw     = (const float*)d_in[1];
    const float* gate_w = (const float*)d_in[2];
    const float* up_w   = (const float*)d_in[3];
    const float* down_w = (const float*)d_in[4];
    const float* gate_b = (const float*)d_in[5];
    const float* up_b   = (const float*)d_in[6];
    const float* down_b = (const float*)d_in[7];
    float* out = (float*)d_out;

    // workspace layout (~85 MB; y2[2 slices, 32 MB] aliases gwt+uwt,
    // which are dead after gateup_wd)
    char* ws = (char*)d_ws;
    size_t off = 0;
    int*   counts   = (int*)(ws + off);  off += 256;
    int*   tok_list = (int*)(ws + off);  off += 65536;
    float* wgt_list = (float*)(ws + off); off += 65536;
    int*   row_list = (int*)(ws + off);  off += 65536;
    int*   sel      = (int*)(ws + off);  off += T_TOK * 4;
    float* w1arr    = (float*)(ws + off); off += T_TOK * 4;
    unsigned short* x_bf = (unsigned short*)(ws + off); off += (size_t)T_TOK * HDIM * 2;       // 4 MB
    unsigned short* act  = (unsigned short*)(ws + off); off += (size_t)2 * T_TOK * IDIM * 2;   // 11.5 MB
    unsigned short* dwt  = (unsigned short*)(ws + off); off += (size_t)NEXP * IDIM * HDIM * 2; // 23 MB
    unsigned short* gwt  = (unsigned short*)(ws + off); off += (size_t)NEXP * IDIM * HDIM * 2; // 23 MB
    unsigned short* uwt  = (unsigned short*)(ws + off);                                        // 23 MB
    float* y2 = (float*)gwt;   // 2 x 16 MB slices, reused after gateup_wd

    prep_kernel<<<PREP_GRID, 256, 0, stream>>>(
        x, rw, gate_w, up_w, sel, w1arr, x_bf, gwt, uwt);

    router_scatter_kernel<<<1, 1024, 0, stream>>>(
        sel, w1arr, counts, tok_list, wgt_list, row_list);

    gateup_wd_kernel<<<GUWD_GRID, 256, 0, stream>>>(
        x_bf, gwt, uwt, gate_b, up_b, counts, tok_list, row_list, act,
        down_w, dwt);

    down_kernel<<<DN_GRID, 256, 0, stream>>>(
        act, dwt, down_b, counts, wgt_list, row_list, y2);

    combine_kernel<<<(T_TOK * HDIM / 4) / 256, 256, 0, stream>>>(y2, out);
}

// Round 11
// 271.485 us; speedup vs baseline: 1.1807x; 1.1807x over previous
//
#include <hip/hip_runtime.h>

// DeepseekV3MoEToA2AAdapter: T=2048 tokens, H=1024, E=8, I=1408, top-2.
// fp32 I/O. Block-range fusion (R6): prep = router || wtrans(g/u);
// gateup_wd = gateup || wtrans(down). DMA staging via global_load_lds
// width=16 (R9). R11: DOUBLE-BUFFERED DMA K-loop — prefetch tile t+1 into
// the other LDS buffer BEFORE computing tile t; one __syncthreads per step
// (its vmcnt(0) drain completes the prefetch, latency hidden under MFMA).
// No extra VGPRs, no ds_writes (R7's dbuf failure modes absent).
#define T_TOK 2048
#define HDIM  1024
#define NEXP  8
#define IDIM  1408

#define BM 128
#define BN 64
#define BK 32
#define MT_SLOTS 16
#define GU_NT 22    // IDIM / BN
#define DN_NT 16    // HDIM / BN
#define DK_HALF 704 // IDIM / 2 (split-K for down)

#define GU_BLOCKS   (8 * GU_NT * MT_SLOTS)   // 2816
#define PREP_RTR    512
#define PREP_GRID   (PREP_RTR + 16 * 176)    // 3328
#define GUWD_GRID   (GU_BLOCKS + 8 * 176)    // 4224

// gateup_wd shared-memory layout (bytes); union with wtrans tb (16896 B)
#define SM_A0   0          // 128*32*2 = 8192
#define SM_A1   8192
#define SM_G0   16384      // 64*32*2 = 4096
#define SM_G1   20480
#define SM_U0   24576
#define SM_U1   28672
#define SM_GR   32768      // 512
#define SM_OR   33280      // 512
#define SM_SZ   33792

typedef __attribute__((ext_vector_type(8))) short bf16x8;
typedef __attribute__((ext_vector_type(4))) float f32x4;

static __device__ __forceinline__ unsigned short f2bf(float f) {
    union { float f; unsigned u; } a; a.f = f;
    return (unsigned short)((a.u + 0x7fffu + ((a.u >> 16) & 1u)) >> 16);
}

// direct global->LDS DMA, 16 B per lane; LDS dest wave-uniform base + lane*16,
// global src per-lane (gather-capable).
#define GLOAD16(gsrc, ldst)                                                  \
    __builtin_amdgcn_global_load_lds(                                        \
        (const __attribute__((address_space(1))) unsigned int*)(gsrc),       \
        (__attribute__((address_space(3))) unsigned int*)(ldst), 16, 0, 0)

// -------- gateup helpers (4 DMA segments / wave / K-step; 2x{A}, Bg, Bu) ----
static __device__ __forceinline__ void gu_stage(
    const unsigned short* apA0, const unsigned short* apA1,
    const unsigned short* gpB, const unsigned short* upB, int k,
    unsigned short* dA0, unsigned short* dA1,
    unsigned short* dBg, unsigned short* dBu)
{
    GLOAD16(apA0 + k, dA0);
    GLOAD16(apA1 + k, dA1);
    GLOAD16(gpB + k, dBg);
    GLOAD16(upB + k, dBu);
}

static __device__ __forceinline__ void gu_mma(
    const unsigned short* As, const unsigned short* Bg,
    const unsigned short* Bu, int wm, int wn, int l16, int quad,
    f32x4 (*accg)[2], f32x4 (*accu)[2])
{
    bf16x8 af[4], bgf[2], bu_[2];
#pragma unroll
    for (int i = 0; i < 4; ++i)
        af[i] = *(const bf16x8*)(As + (wm + i * 16 + l16) * 32 + quad * 8);
#pragma unroll
    for (int j = 0; j < 2; ++j) {
        bgf[j] = *(const bf16x8*)(Bg + (wn + j * 16 + l16) * 32 + quad * 8);
        bu_[j] = *(const bf16x8*)(Bu + (wn + j * 16 + l16) * 32 + quad * 8);
    }
#pragma unroll
    for (int i = 0; i < 4; ++i)
#pragma unroll
        for (int j = 0; j < 2; ++j) {
            accg[i][j] = __builtin_amdgcn_mfma_f32_16x16x32_bf16(
                af[i], bgf[j], accg[i][j], 0, 0, 0);
            accu[i][j] = __builtin_amdgcn_mfma_f32_16x16x32_bf16(
                af[i], bu_[j], accu[i][j], 0, 0, 0);
        }
}

// -------- down helpers (3 DMA segments / wave / K-step) ---------------------
static __device__ __forceinline__ void dn_mma(
    const unsigned short* As, const unsigned short* Bs,
    int wm, int wn, int l16, int quad, f32x4 (*acc)[2])
{
    bf16x8 af[4], bfr[2];
#pragma unroll
    for (int i = 0; i < 4; ++i)
        af[i] = *(const bf16x8*)(As + (wm + i * 16 + l16) * 32 + quad * 8);
#pragma unroll
    for (int j = 0; j < 2; ++j)
        bfr[j] = *(const bf16x8*)(Bs + (wn + j * 16 + l16) * 32 + quad * 8);
#pragma unroll
    for (int i = 0; i < 4; ++i)
#pragma unroll
        for (int j = 0; j < 2; ++j)
            acc[i][j] = __builtin_amdgcn_mfma_f32_16x16x32_bf16(
                af[i], bfr[j], acc[i][j], 0, 0, 0);
}

// ---------------------------------------------------------------- prep ------
// blocks [0,512): router pass 1. blocks [512,3328): gate/up cast+transpose.
__global__ __launch_bounds__(256) void prep_kernel(
    const float* __restrict__ x,        // [T, H]
    const float* __restrict__ rw,       // [H, E]
    const float* __restrict__ gw,       // [E][H][I] fp32
    const float* __restrict__ uw,       // [E][H][I] fp32
    int*   __restrict__ sel,            // [T]
    float* __restrict__ w1arr,          // [T]
    unsigned short* __restrict__ xb,    // [T, H] bf16
    unsigned short* __restrict__ gwt,   // [E][I][H] bf16
    unsigned short* __restrict__ uwt)   // [E][I][H] bf16
{
    __shared__ __align__(16) char smem[32768];
    const int tid = threadIdx.x;
    const int bx  = blockIdx.x;

    if (bx < PREP_RTR) {
        float (*rwT)[HDIM] = (float (*)[HDIM])smem;   // 32 KB
#pragma unroll
        for (int p = 0; p < 4; ++p) {
            const int h = tid + 256 * p;
            const float4 a = *(const float4*)(rw + (size_t)h * 8);
            const float4 b = *(const float4*)(rw + (size_t)h * 8 + 4);
            rwT[0][h] = a.x; rwT[1][h] = a.y; rwT[2][h] = a.z; rwT[3][h] = a.w;
            rwT[4][h] = b.x; rwT[5][h] = b.y; rwT[6][h] = b.z; rwT[7][h] = b.w;
        }
        __syncthreads();

        const int t    = bx * 4 + (tid >> 6);
        const int lane = tid & 63;
        if (t >= T_TOK) return;

        float xr[16];
        const float* xp = x + (size_t)t * HDIM;
#pragma unroll
        for (int i = 0; i < 16; ++i) xr[i] = xp[lane + 64 * i];

        unsigned short* xbp = xb + (size_t)t * HDIM;
#pragma unroll
        for (int i = 0; i < 16; ++i) xbp[lane + 64 * i] = f2bf(xr[i]);

        double logits[NEXP];
#pragma unroll
        for (int e = 0; e < NEXP; ++e) {
            double s = 0.0;
#pragma unroll
            for (int i = 0; i < 16; ++i)
                s += (double)xr[i] * (double)rwT[e][lane + 64 * i];
#pragma unroll
            for (int off = 32; off > 0; off >>= 1)
                s += __shfl_down(s, off, 64);
            logits[e] = s;
        }

        if (lane == 0) {
            int e1 = 0;
            for (int e = 1; e < NEXP; ++e) if (logits[e] > logits[e1]) e1 = e;
            int e2 = -1;
            for (int e = 0; e < NEXP; ++e) {
                if (e == e1) continue;
                if (e2 < 0 || logits[e] > logits[e2]) e2 = e;
            }
            const double w1 = 1.0 / (1.0 + exp(logits[e2] - logits[e1]));
            sel[t]   = e1 | (e2 << 8);
            w1arr[t] = (float)w1;
        }
    } else {
        const int idx = bx - PREP_RTR;
        const int z   = idx / 176;          // 0..15
        const int b   = idx - z * 176;      // 0..175
        const int e   = z & 7;
        const float* src = (z < 8 ? gw : uw) + (size_t)e * HDIM * IDIM;
        unsigned short* dst =
            (z < 8 ? gwt : uwt) + (size_t)e * (size_t)IDIM * HDIM;
        const int nb = b % 11, kb = b / 11;  // 11 n-tiles x 16 k-tiles
        const int k0 = kb * 64, n0 = nb * 128;

        unsigned short (*tb)[66] = (unsigned short (*)[66])smem; // 16.9 KB

        const int lk = tid >> 5;            // 0..7
        const int ln = (tid & 31) * 4;      // 0..124
#pragma unroll
        for (int r = 0; r < 8; ++r) {
            const int k = r * 8 + lk;
            const float4 v =
                *(const float4*)(src + (size_t)(k0 + k) * IDIM + n0 + ln);
            tb[ln + 0][k] = f2bf(v.x);
            tb[ln + 1][k] = f2bf(v.y);
            tb[ln + 2][k] = f2bf(v.z);
            tb[ln + 3][k] = f2bf(v.w);
        }
        __syncthreads();

        const int wn = tid >> 3;            // 0..31
        const int wk = (tid & 7) * 8;       // 0..56
#pragma unroll
        for (int p = 0; p < 4; ++p) {
            const int n = p * 32 + wn;
            const unsigned* rp = (const unsigned*)&tb[n][wk];
            uint4 o;
            o.x = rp[0]; o.y = rp[1]; o.z = rp[2]; o.w = rp[3];
            *(uint4*)(dst + (size_t)(n0 + n) * HDIM + k0 + wk) = o;
        }
    }
}

// ------------------------------------------- router pass 2: scatter ---------
__global__ __launch_bounds__(1024) void router_scatter_kernel(
    const int* __restrict__ sel, const float* __restrict__ w1arr,
    int* __restrict__ counts,
    int* __restrict__ tok_list, float* __restrict__ wgt_list,
    int* __restrict__ row_list)
{
    __shared__ int cnt[NEXP];
    const int tid = threadIdx.x;
    if (tid < NEXP) cnt[tid] = 0;
    __syncthreads();
    for (int t = tid; t < T_TOK; t += 1024) {
        const int s  = sel[t];
        const int e1 = s & 255, e2 = s >> 8;
        const float w1 = w1arr[t];
        const int p1 = atomicAdd(&cnt[e1], 1);
        tok_list[e1 * T_TOK + p1] = t;
        wgt_list[e1 * T_TOK + p1] = w1;
        row_list[e1 * T_TOK + p1] = 2 * t;
        const int p2 = atomicAdd(&cnt[e2], 1);
        tok_list[e2 * T_TOK + p2] = t;
        wgt_list[e2 * T_TOK + p2] = 1.0f - w1;
        row_list[e2 * T_TOK + p2] = 2 * t + 1;
    }
    __syncthreads();
    if (tid < NEXP) counts[tid] = cnt[tid];
}

// -------------------------------- fused gate+up GEMM || wtrans(down) --------
// blocks [0,2816): gateup BM=128/BN=64/BK=32, 4 waves, DMA dbuf staging.
// blocks [2816,4224): down_proj cast+transpose.
__global__ __launch_bounds__(256) void gateup_wd_kernel(
    const unsigned short* __restrict__ xb,    // [T,H] bf16
    const unsigned short* __restrict__ gwt,   // [E][I][H] bf16
    const unsigned short* __restrict__ uwt,   // [E][I][H] bf16
    const float* __restrict__ gb, const float* __restrict__ ub,
    const int* __restrict__ counts,
    const int* __restrict__ tok_list,
    const int* __restrict__ row_list,
    unsigned short* __restrict__ act,         // [2T, IDIM] bf16
    const float* __restrict__ dw,             // [E][I][H] fp32
    unsigned short* __restrict__ dwt)         // [E][H][I] bf16
{
    __shared__ __align__(16) char smem[SM_SZ];
    const int tid  = threadIdx.x;
    const int flat = blockIdx.x;

    if (flat >= GU_BLOCKS) {
        // ------------------------------ wtrans down ---------------------
        const int idx = flat - GU_BLOCKS;
        const int e   = idx / 176;
        const int b   = idx - e * 176;
        const float* src = dw + (size_t)e * IDIM * HDIM;   // [I][H] fp32
        unsigned short* dst = dwt + (size_t)e * (size_t)HDIM * IDIM;
        const int nb = b & 7, kb = b >> 3;   // 8 n-tiles x 22 k-tiles
        const int k0 = kb * 64, n0 = nb * 128;

        unsigned short (*tb)[66] = (unsigned short (*)[66])smem;

        const int lk = tid >> 5;
        const int ln = (tid & 31) * 4;
#pragma unroll
        for (int r = 0; r < 8; ++r) {
            const int k = r * 8 + lk;
            const float4 v =
                *(const float4*)(src + (size_t)(k0 + k) * HDIM + n0 + ln);
            tb[ln + 0][k] = f2bf(v.x);
            tb[ln + 1][k] = f2bf(v.y);
            tb[ln + 2][k] = f2bf(v.z);
            tb[ln + 3][k] = f2bf(v.w);
        }
        __syncthreads();

        const int wn = tid >> 3;
        const int wk = (tid & 7) * 8;
#pragma unroll
        for (int p = 0; p < 4; ++p) {
            const int n = p * 32 + wn;
            const unsigned* rp = (const unsigned*)&tb[n][wk];
            uint4 o;
            o.x = rp[0]; o.y = rp[1]; o.z = rp[2]; o.w = rp[3];
            *(uint4*)(dst + (size_t)(n0 + n) * IDIM + k0 + wk) = o;
        }
        return;
    }

    // ---------------------------------- gateup (DMA dbuf) ---------------
    int* gr_lds = (int*)(smem + SM_GR);
    int* or_lds = (int*)(smem + SM_OR);

    const int xcd  = flat & 7;
    const int q    = flat >> 3;
    const int mt   = q & 15;
    const int slot = q >> 4;
    const int P    = slot * 8 + xcd;   // 0..175 = (e, nt), fixed XCD per (e,nt)
    const int e    = P / GU_NT;
    const int nt   = P % GU_NT;
    const int n_e  = counts[e];
    const int m0   = mt * BM;
    if (m0 >= n_e) return;
    const int n0 = nt * BN;

    const unsigned short* gwp = gwt + (size_t)e * IDIM * HDIM;
    const unsigned short* uwp = uwt + (size_t)e * IDIM * HDIM;
    const float* gbp = gb + (size_t)e * IDIM;
    const float* ubp = ub + (size_t)e * IDIM;

    const int base = e * T_TOK;
    if (tid < BM) {
        const int m = m0 + tid;
        int g = -1, o = -1;
        if (m < n_e) { g = tok_list[base + m]; o = row_list[base + m]; }
        gr_lds[tid] = g; or_lds[tid] = o;
    }
    __syncthreads();

    const int wv = tid >> 6, lane = tid & 63;
    const int lr = lane >> 2;           // 0..15 (row within 16-row segment)
    const int lc = (lane & 3) * 8;      // col element (16 B chunks)

    // per-wave DMA sources (gathered token rows for A)
    const int r0 = 32 * wv + lr;
    const int r1 = r0 + 16;
    int a0 = gr_lds[r0]; if (a0 < 0) a0 = 0;
    int a1 = gr_lds[r1]; if (a1 < 0) a1 = 0;
    const unsigned short* apA0 = xb + (size_t)a0 * HDIM + lc;
    const unsigned short* apA1 = xb + (size_t)a1 * HDIM + lc;
    const unsigned short* gpB = gwp + (size_t)(n0 + 16 * wv + lr) * HDIM + lc;
    const unsigned short* upB = uwp + (size_t)(n0 + 16 * wv + lr) * HDIM + lc;

    // per-wave DMA dests, both buffers (element offsets within a tile)
    const int oA0 = (32 * wv) * 32;
    const int oA1 = (32 * wv + 16) * 32;
    const int oB  = (16 * wv) * 32;
    unsigned short* A0b = (unsigned short*)(smem + SM_A0);
    unsigned short* A1b = (unsigned short*)(smem + SM_A1);
    unsigned short* G0b = (unsigned short*)(smem + SM_G0);
    unsigned short* G1b = (unsigned short*)(smem + SM_G1);
    unsigned short* U0b = (unsigned short*)(smem + SM_U0);
    unsigned short* U1b = (unsigned short*)(smem + SM_U1);

    const int wm = (wv & 1) * 64, wn = (wv >> 1) * 32;
    const int l16 = lane & 15, quad = lane >> 4;

    f32x4 accg[4][2], accu[4][2];
    const f32x4 zero = {0.0f, 0.0f, 0.0f, 0.0f};
#pragma unroll
    for (int i = 0; i < 4; ++i)
#pragma unroll
        for (int j = 0; j < 2; ++j) { accg[i][j] = zero; accu[i][j] = zero; }

    // prologue: tile 0 -> buf0
    gu_stage(apA0, apA1, gpB, upB, 0,
             A0b + oA0, A0b + oA1, G0b + oB, U0b + oB);
    __syncthreads();

    for (int k0 = 0; k0 < HDIM; k0 += 2 * BK) {
        // phase 0: prefetch k0+BK -> buf1 (always valid: k0+BK <= 992)
        gu_stage(apA0, apA1, gpB, upB, k0 + BK,
                 A1b + oA0, A1b + oA1, G1b + oB, U1b + oB);
        gu_mma(A0b, G0b, U0b, wm, wn, l16, quad, accg, accu);
        __syncthreads();
        // phase 1: prefetch k0+2BK -> buf0 (if any), compute buf1
        if (k0 + 2 * BK < HDIM)
            gu_stage(apA0, apA1, gpB, upB, k0 + 2 * BK,
                     A0b + oA0, A0b + oA1, G0b + oB, U0b + oB);
        gu_mma(A1b, G1b, U1b, wm, wn, l16, quad, accg, accu);
        __syncthreads();
    }

    // epilogue: silu(g)*u -> bf16 act
#pragma unroll
    for (int j = 0; j < 2; ++j) {
        const int nl = n0 + wn + j * 16 + l16;
        const float gbv = gbp[nl];
        const float ubv = ubp[nl];
#pragma unroll
        for (int i = 0; i < 4; ++i) {
#pragma unroll
            for (int ii = 0; ii < 4; ++ii) {
                const int ml = wm + i * 16 + quad * 4 + ii;
                const int orow = or_lds[ml];
                if (orow >= 0) {
                    const float g = accg[i][j][ii] + gbv;
                    const float uu = accu[i][j][ii] + ubv;
                    act[(size_t)orow * IDIM + nl] =
                        f2bf(g * uu / (1.0f + __expf(-g)));
                }
            }
        }
    }
}

// ------------------------------------------------------- down-proj GEMM ----
// Split-K=2, NON-ATOMIC; DMA dbuf staging (22 K-steps = 11 double-steps).
__global__ __launch_bounds__(256) void down_kernel(
    const unsigned short* __restrict__ act,   // [2T, IDIM] bf16
    const unsigned short* __restrict__ dwt,   // [E][H][I] bf16
    const float* __restrict__ db,
    const int* __restrict__ counts,
    const float* __restrict__ wgt_list,
    const int* __restrict__ row_list,
    float* __restrict__ y2)                   // [2][2T, HDIM] fp32
{
    const int flat = blockIdx.x;
    const int xcd  = flat & 7;
    const int q    = flat >> 3;
    const int mt   = q & 15;
    const int slot = q >> 4;
    const int P    = slot * 8 + xcd;   // 0..255 = (sk, e, nt)
    const int sk   = P & 1;
    const int en   = P >> 1;
    const int e    = en >> 4;
    const int nt   = en & 15;
    const int n_e  = counts[e];
    const int m0   = mt * BM;
    if (m0 >= n_e) return;
    const int n0 = nt * BN;
    const int ks = sk * DK_HALF;
    float* y2s = y2 + (size_t)sk * 2 * T_TOK * HDIM;

    const unsigned short* dwp = dwt + (size_t)e * HDIM * IDIM;
    const float* dbp = db + (size_t)e * HDIM;

    __shared__ unsigned short As0[BM][32], As1[BM][32];  // 16 KB
    __shared__ unsigned short Bs0[BN][32], Bs1[BN][32];  //  8 KB
    __shared__ int   r_lds[BM];
    __shared__ float w_lds[BM];

    const int tid = threadIdx.x;
    const int base = e * T_TOK;
    if (tid < BM) {
        const int m = m0 + tid;
        int r = -1; float w = 0.0f;
        if (m < n_e) { r = row_list[base + m]; w = wgt_list[base + m]; }
        r_lds[tid] = r; w_lds[tid] = w;
    }
    __syncthreads();

    const int wv = tid >> 6, lane = tid & 63;
    const int lr = lane >> 2;
    const int lc = (lane & 3) * 8;

    const int r0 = 32 * wv + lr;
    const int r1 = r0 + 16;
    int a0 = r_lds[r0]; if (a0 < 0) a0 = 0;
    int a1 = r_lds[r1]; if (a1 < 0) a1 = 0;
    const unsigned short* apA0 = act + (size_t)a0 * IDIM + ks + lc;
    const unsigned short* apA1 = act + (size_t)a1 * IDIM + ks + lc;
    const unsigned short* bpB =
        dwp + (size_t)(n0 + 16 * wv + lr) * IDIM + ks + lc;
    unsigned short* dA0_0 = &As0[32 * wv][0];
    unsigned short* dA1_0 = &As0[32 * wv + 16][0];
    unsigned short* dA0_1 = &As1[32 * wv][0];
    unsigned short* dA1_1 = &As1[32 * wv + 16][0];
    unsigned short* dB_0  = &Bs0[16 * wv][0];
    unsigned short* dB_1  = &Bs1[16 * wv][0];

    const int wm = (wv & 1) * 64, wn = (wv >> 1) * 32;
    const int l16 = lane & 15, quad = lane >> 4;

    f32x4 acc[4][2];
    const f32x4 zero = {0.0f, 0.0f, 0.0f, 0.0f};
#pragma unroll
    for (int i = 0; i < 4; ++i)
#pragma unroll
        for (int j = 0; j < 2; ++j) acc[i][j] = zero;

    // prologue: tile 0 -> buf0
    GLOAD16(apA0, dA0_0);
    GLOAD16(apA1, dA1_0);
    GLOAD16(bpB, dB_0);
    __syncthreads();

    for (int k0 = 0; k0 < DK_HALF; k0 += 2 * BK) {
        // phase 0: prefetch k0+BK -> buf1 (always valid: k0+BK <= 672)
        GLOAD16(apA0 + k0 + BK, dA0_1);
        GLOAD16(apA1 + k0 + BK, dA1_1);
        GLOAD16(bpB + k0 + BK, dB_1);
        dn_mma(&As0[0][0], &Bs0[0][0], wm, wn, l16, quad, acc);
        __syncthreads();
        // phase 1: prefetch k0+2BK -> buf0 (if any), compute buf1
        if (k0 + 2 * BK < DK_HALF) {
            GLOAD16(apA0 + k0 + 2 * BK, dA0_0);
            GLOAD16(apA1 + k0 + 2 * BK, dA1_0);
            GLOAD16(bpB + k0 + 2 * BK, dB_0);
        }
        dn_mma(&As1[0][0], &Bs1[0][0], wm, wn, l16, quad, acc);
        __syncthreads();
    }

#pragma unroll
    for (int j = 0; j < 2; ++j) {
        const int nl = n0 + wn + j * 16 + l16;
        const float bv = (sk == 0) ? dbp[nl] : 0.0f;
#pragma unroll
        for (int i = 0; i < 4; ++i) {
#pragma unroll
            for (int ii = 0; ii < 4; ++ii) {
                const int ml = wm + i * 16 + quad * 4 + ii;
                const int rr = r_lds[ml];
                if (rr >= 0)
                    y2s[(size_t)rr * HDIM + nl] = w_lds[ml] * (acc[i][j][ii] + bv);
            }
        }
    }
}

// --------------------------------------------------------------- combine ----
__global__ __launch_bounds__(256) void combine_kernel(
    const float* __restrict__ y2, float* __restrict__ out)
{
    const int idx = (blockIdx.x * 256 + threadIdx.x) * 4;   // < T*H
    const int t = idx >> 10;           // HDIM == 1024
    const int h = idx & 1023;
    const float* y2b = y2 + (size_t)2 * T_TOK * HDIM;
    const float4 a0 = *(const float4*)(y2  + ((size_t)2 * t) * HDIM + h);
    const float4 a1 = *(const float4*)(y2  + ((size_t)2 * t + 1) * HDIM + h);
    const float4 b0 = *(const float4*)(y2b + ((size_t)2 * t) * HDIM + h);
    const float4 b1 = *(const float4*)(y2b + ((size_t)2 * t + 1) * HDIM + h);
    float4 o;
    o.x = a0.x + a1.x + b0.x + b1.x;
    o.y = a0.y + a1.y + b0.y + b1.y;
    o.z = a0.z + a1.z + b0.z + b1.z;
    o.w = a0.w + a1.w + b0.w + b1.w;
    *(float4*)(out + idx) = o;
}

// ---------------------------------------------------------------- launch ----
extern "C" void kernel_launch(void* const* d_in, const int* in_sizes, int n_in,
                              void* d_out, int out_size, void* d_ws, size_t ws_size,
                              hipStream_t stream)
{
    const float* x      = (const float*)d_in[0];
    const float* rw     = (const float*)d_in[1];
    const float* gate_w = (const float*)d_in[2];
    const float* up_w   = (const float*)d_in[3];
    const float* down_w = (const float*)d_in[4];
    const float* gate_b = (const float*)d_in[5];
    const float* up_b   = (const float*)d_in[6];
    const float* down_b = (const float*)d_in[7];
    float* out = (float*)d_out;

    // workspace layout (~85 MB; y2[2 slices, 32 MB] aliases gwt+uwt,
    // which are dead after gateup_wd)
    char* ws = (char*)d_ws;
    size_t off = 0;
    int*   counts   = (int*)(ws + off);  off += 256;
    int*   tok_list = (int*)(ws + off);  off += 65536;
    float* wgt_list = (float*)(ws + off); off += 65536;
    int*   row_list = (int*)(ws + off);  off += 65536;
    int*   sel      = (int*)(ws + off);  off += T_TOK * 4;
    float* w1arr    = (float*)(ws + off); off += T_TOK * 4;
    unsigned short* x_bf = (unsigned short*)(ws + off); off += (size_t)T_TOK * HDIM * 2;       // 4 MB
    unsigned short* act  = (unsigned short*)(ws + off); off += (size_t)2 * T_TOK * IDIM * 2;   // 11.5 MB
    unsigned short* dwt  = (unsigned short*)(ws + off); off += (size_t)NEXP * IDIM * HDIM * 2; // 23 MB
    unsigned short* gwt  = (unsigned short*)(ws + off); off += (size_t)NEXP * IDIM * HDIM * 2; // 23 MB
    unsigned short* uwt  = (unsigned short*)(ws + off);                                        // 23 MB
    float* y2 = (float*)gwt;   // 2 x 16 MB slices, reused after gateup_wd

    prep_kernel<<<PREP_GRID, 256, 0, stream>>>(
        x, rw, gate_w, up_w, sel, w1arr, x_bf, gwt, uwt);

    router_scatter_kernel<<<1, 1024, 0, stream>>>(
        sel, w1arr, counts, tok_list, wgt_list, row_list);

    gateup_wd_kernel<<<GUWD_GRID, 256, 0, stream>>>(
        x_bf, gwt, uwt, gate_b, up_b, counts, tok_list, row_list, act,
        down_w, dwt);

    down_kernel<<<2 * 8 * DN_NT * MT_SLOTS, 256, 0, stream>>>(
        act, dwt, down_b, counts, wgt_list, row_list, y2);

    combine_kernel<<<(T_TOK * HDIM / 4) / 256, 256, 0, stream>>>(y2, out);
}